// Round 7
// baseline (1962.904 us; speedup 1.0000x reference)
//
#include <hip/hip_runtime.h>
#include <hip/hip_bf16.h>

typedef __hip_bfloat16 bf16;
typedef short short8 __attribute__((ext_vector_type(8)));   // 8 bf16 bit-patterns (4 VGPRs)
typedef float floatx4 __attribute__((ext_vector_type(4)));
typedef int int4v __attribute__((ext_vector_type(4)));

#define DIMC 1152
#define NTOK 8192    // B*N
#define NSEQ 4096
#define HD 72
#define HDP 73       // HD + 1 (padded-ones value column)
#define HIDC 4608
#define HID2 9216
#define KVH (HD * HDP)            // 5256 per (b,h)
#define KVELEMS (32 * KVH)

__device__ __forceinline__ float b2f(bf16 x) { return __bfloat162float(x); }
__device__ __forceinline__ bf16 f2b(float x) { return __float2bfloat16(x); }
__device__ __forceinline__ void st(float* p, float v) { *p = v; }
__device__ __forceinline__ void st(bf16* p, float v)  { *p = f2b(v); }

// ---------------- f32 -> bf16 weight conversion ----------------
__global__ void cvt_w_kernel(const float* __restrict__ src, bf16* __restrict__ dst, int n4) {
    int i = blockIdx.x * 256 + threadIdx.x;
    if (i >= n4) return;
    floatx4 v = ((const floatx4*)src)[i];
    bf16* o = dst + (size_t)i * 4;
    o[0] = f2b(v[0]); o[1] = f2b(v[1]); o[2] = f2b(v[2]); o[3] = f2b(v[3]);
}

__global__ void zero_kernel(float* __restrict__ p, int n) {
    int i = blockIdx.x * 256 + threadIdx.x;
    if (i < n) p[i] = 0.0f;
}

// ---------------- mods = scale_shift_table + temb.reshape(B,6,D) ----------------
__global__ void mods_kernel(const float* __restrict__ sst, const float* __restrict__ temb,
                            float* __restrict__ mods) {
    int i = blockIdx.x * 256 + threadIdx.x;
    if (i < 2 * 6 * DIMC) {
        int j = i % (6 * DIMC);
        mods[i] = sst[j] + temb[i];
    }
}

// ---------------- x = rms(h)*(1+scale)+shift; h is f32; out bf16 ----------------
__global__ void rmsmod_kernel(const float* __restrict__ h, const float* __restrict__ mods,
                              int shift_idx, int scale_idx, bf16* __restrict__ xout) {
    int token = blockIdx.x;            // 0..8191
    int b = token >> 12;
    int tid = threadIdx.x;
    int wave = tid >> 6, lane = tid & 63;
    const float* hp = h + (size_t)token * DIMC;

    float s = 0.f;
    for (int d = tid; d < DIMC; d += 256) { float v = hp[d]; s += v * v; }
    #pragma unroll
    for (int off = 32; off > 0; off >>= 1) s += __shfl_down(s, off);
    __shared__ float wsum[4];
    if (lane == 0) wsum[wave] = s;
    __syncthreads();
    float tot = wsum[0] + wsum[1] + wsum[2] + wsum[3];
    float r = rsqrtf(tot / (float)DIMC + 1e-6f);

    const float* sh = mods + (size_t)(b * 6 + shift_idx) * DIMC;
    const float* sc = mods + (size_t)(b * 6 + scale_idx) * DIMC;
    bf16* xo = xout + (size_t)token * DIMC;
    for (int d = tid; d < DIMC; d += 256) {
        float v = hp[d];
        xo[d] = f2b(v * r * (1.f + sc[d]) + sh[d]);
    }
}

// ---------------- MFMA GEMM: out = epilogue(A @ W^T); A (M,K) bf16, W (N,K) bf16 ----------------
// (engine validated in R5: VALU swap produced bit-identical output)
// MODE 0: relu(acc+bias)            -> bf16   (Q,K proj)
// MODE 1: acc+bias                  -> bf16   (V proj)
// MODE 2: gate*(acc+bias)+resid     -> f32    (Wo + residual; resid = h_in f32)
// MODE 3: silu(acc+bias)            -> bf16   (W_inv)
// MODE 4: resid + gate*acc          -> f32    (W_pt + final residual; resid f32 trunk)
// bm tiles outside [bm_lo,bm_hi) skipped (128-row units). batch = (m+m_off)>>12.
template<int MODE, typename OT>
__global__ __launch_bounds__(256, 2)
void gemm_kernel(const bf16* __restrict__ A, const bf16* __restrict__ W,
                 const float* __restrict__ bias, const float* __restrict__ mods,
                 int gate_idx, int m_off, const float* __restrict__ resid,
                 OT* __restrict__ out, int N, int K, int bm_lo, int bm_hi) {
    const int bm = blockIdx.x;
    if (bm < bm_lo || bm >= bm_hi) return;
    __shared__ short As[128 * 40];   // 128 rows x 32 k, padded stride 40
    __shared__ short Bs[128 * 40];
    const int tid = threadIdx.x;
    const int wave = tid >> 6;
    const int lane = tid & 63;
    const int quad = lane >> 4;
    const int l16 = lane & 15;
    const int wm = (wave & 1) * 64;
    const int wn = (wave >> 1) * 64;
    const int bn = blockIdx.y;

    floatx4 acc[4][4];
    #pragma unroll
    for (int i = 0; i < 4; i++)
        #pragma unroll
        for (int j = 0; j < 4; j++)
            #pragma unroll
            for (int r = 0; r < 4; r++) acc[i][j][r] = 0.0f;

    const int c0 = tid, c1 = tid + 256;
    const int ar0 = c0 >> 2, ac0 = (c0 & 3) * 8;
    const int ar1 = c1 >> 2, ac1 = (c1 & 3) * 8;
    const bf16* Abase = A + (size_t)(bm * 128) * K;
    const bf16* Wbase = W + (size_t)(bn * 128) * K;

    for (int k0 = 0; k0 < K; k0 += 32) {
        __syncthreads();
        *(int4v*)&As[ar0 * 40 + ac0] = *(const int4v*)(Abase + (size_t)ar0 * K + k0 + ac0);
        *(int4v*)&As[ar1 * 40 + ac1] = *(const int4v*)(Abase + (size_t)ar1 * K + k0 + ac1);
        *(int4v*)&Bs[ar0 * 40 + ac0] = *(const int4v*)(Wbase + (size_t)ar0 * K + k0 + ac0);
        *(int4v*)&Bs[ar1 * 40 + ac1] = *(const int4v*)(Wbase + (size_t)ar1 * K + k0 + ac1);
        __syncthreads();
        short8 af[4], bfr[4];
        #pragma unroll
        for (int i = 0; i < 4; i++) {
            af[i]  = *(const short8*)&As[(wm + i * 16 + l16) * 40 + quad * 8];
            bfr[i] = *(const short8*)&Bs[(wn + i * 16 + l16) * 40 + quad * 8];
        }
        #pragma unroll
        for (int i = 0; i < 4; i++)
            #pragma unroll
            for (int j = 0; j < 4; j++)
                acc[i][j] = __builtin_amdgcn_mfma_f32_16x16x32_bf16(af[i], bfr[j], acc[i][j], 0, 0, 0);
    }

    #pragma unroll
    for (int i = 0; i < 4; i++) {
        #pragma unroll
        for (int j = 0; j < 4; j++) {
            const int col = bn * 128 + wn + j * 16 + l16;
            #pragma unroll
            for (int r = 0; r < 4; r++) {
                const int m = bm * 128 + wm + i * 16 + quad * 4 + r;
                float v = acc[i][j][r];
                float o;
                if (MODE == 0) { o = fmaxf(v + bias[col], 0.f); }
                else if (MODE == 1) { o = v + bias[col]; }
                else if (MODE == 2) {
                    int b = (m + m_off) >> 12;
                    o = mods[(size_t)(b * 6 + gate_idx) * DIMC + col] * (v + bias[col])
                        + resid[(size_t)m * DIMC + col];
                } else if (MODE == 3) {
                    float sv = v + bias[col];
                    o = sv / (1.f + __expf(-sv));
                } else {  // MODE 4
                    int b = (m + m_off) >> 12;
                    o = resid[(size_t)m * DIMC + col]
                        + mods[(size_t)(b * 6 + gate_idx) * DIMC + col] * v;
                }
                st(&out[(size_t)m * N + col], o);
            }
        }
    }
}

// ---------------- attention phase A (per batch): kv[h][d][e] += sum_n k[n,d]*vpad[n,e] ----------------
__global__ __launch_bounds__(256)
void attn_kv_kernel(const bf16* __restrict__ k, const bf16* __restrict__ v,
                    float* __restrict__ kv) {
    int chunk = blockIdx.x;   // 32 chunks of 128 tokens
    int h = blockIdx.y;       // 16 heads
    __shared__ bf16 kl[128 * HD];
    __shared__ bf16 vl[128 * HDP];
    int tid = threadIdx.x;
    size_t rowbase = ((size_t)chunk * 128) * DIMC + h * HD;
    for (int idx = tid; idx < 128 * HD; idx += 256) {
        int n = idx / HD, d = idx % HD;
        kl[idx] = k[rowbase + (size_t)n * DIMC + d];
    }
    for (int idx = tid; idx < 128 * HDP; idx += 256) {
        int n = idx / HDP, e = idx % HDP;
        vl[idx] = (e == HD) ? f2b(1.0f) : v[rowbase + (size_t)n * DIMC + e];
    }
    __syncthreads();
    for (int cell = tid; cell < KVH; cell += 256) {
        int d = cell / HDP, e = cell % HDP;
        float acc = 0.f;
        #pragma unroll 8
        for (int n = 0; n < 128; ++n)
            acc += b2f(kl[n * HD + d]) * b2f(vl[n * HDP + e]);
        atomicAdd(&kv[(size_t)h * KVH + cell], acc);
    }
}

// ---------------- attention phase B (per batch): out[n,e] = (q.kv[:,e]) / (q.kv[:,72]+eps) ----------------
__global__ __launch_bounds__(256, 2)
void attn_out_kernel(const bf16* __restrict__ q, const float* __restrict__ kv,
                     bf16* __restrict__ outa) {
    int chunk = blockIdx.x;
    int h = blockIdx.y;
    __shared__ float kvt[HDP * HD];   // kvt[e*72+d]
    __shared__ bf16 ql[128 * HD];
    int tid = threadIdx.x;
    for (int i = tid; i < KVH; i += 256) {
        int d = i / HDP, e = i % HDP;
        kvt[e * HD + d] = kv[(size_t)h * KVH + i];
    }
    size_t rowbase = ((size_t)chunk * 128) * DIMC + h * HD;
    for (int idx = tid; idx < 128 * HD; idx += 256) {
        int n = idx / HD, d = idx % HD;
        ql[idx] = q[rowbase + (size_t)n * DIMC + d];
    }
    __syncthreads();
    int n = tid >> 1;
    int hf = tid & 1;
    float qr[HD];
    #pragma unroll
    for (int d = 0; d < HD; ++d) qr[d] = b2f(ql[n * HD + d]);
    float den = 0.f;
    #pragma unroll
    for (int d = 0; d < HD; ++d) den += qr[d] * kvt[HD * HD + d];
    den += 1e-15f;
    float inv = 1.0f / den;
    for (int ei = 0; ei < 36; ++ei) {
        int e = hf * 36 + ei;
        const float* kr = &kvt[e * HD];
        float s = 0.f;
        #pragma unroll
        for (int d = 0; d < HD; ++d) s += qr[d] * kr[d];
        outa[rowbase + (size_t)n * DIMC + e] = f2b(s * inv);
    }
}

// ---------------- depthwise conv k=3 + bias + GLU(silu), chunked with 128-row halo ----------------
// ybuf holds rows [r0-128, r0+1152) of this batch; buf row = global - (r0-128).
__global__ void dwglu_kernel(const bf16* __restrict__ ybuf, const float* __restrict__ wdw,
                             const float* __restrict__ bdw, int r0, bf16* __restrict__ outg) {
    int nl = blockIdx.x;                        // 0..1023 local
    int g = r0 + nl;                            // global row within batch
    int c = blockIdx.y * 256 + threadIdx.x;     // 0..4607
    int row = nl + 128;
    size_t base = (size_t)row * HID2;
    int cg = c + HIDC;
    float xm1 = (g > 0)        ? b2f(ybuf[base - HID2 + c])  : 0.f;
    float x0  =                  b2f(ybuf[base + c]);
    float xp1 = (g < NSEQ - 1) ? b2f(ybuf[base + HID2 + c])  : 0.f;
    float gm1 = (g > 0)        ? b2f(ybuf[base - HID2 + cg]) : 0.f;
    float g0  =                  b2f(ybuf[base + cg]);
    float gp1 = (g < NSEQ - 1) ? b2f(ybuf[base + HID2 + cg]) : 0.f;
    float a = xm1 * wdw[c * 3 + 0] + x0 * wdw[c * 3 + 1] + xp1 * wdw[c * 3 + 2] + bdw[c];
    float gg = gm1 * wdw[cg * 3 + 0] + g0 * wdw[cg * 3 + 1] + gp1 * wdw[cg * 3 + 2] + bdw[cg];
    float sg = gg / (1.f + __expf(-gg));
    outg[(size_t)nl * HIDC + c] = f2b(a * sg);
}

extern "C" void kernel_launch(void* const* d_in, const int* in_sizes, int n_in,
                              void* d_out, int out_size, void* d_ws, size_t ws_size,
                              hipStream_t stream) {
    // Inputs: FLOAT32 (per reference setup_inputs). Output: FLOAT32 (reference output dtype).
    const float* h_in = (const float*)d_in[0];
    const float* temb = (const float*)d_in[1];
    const float* sst  = (const float*)d_in[2];
    const float* Wq = (const float*)d_in[3];   const float* bq_ = (const float*)d_in[4];
    const float* Wk = (const float*)d_in[5];   const float* bk_ = (const float*)d_in[6];
    const float* Wv = (const float*)d_in[7];   const float* bv_ = (const float*)d_in[8];
    const float* Wo = (const float*)d_in[9];   const float* bo_ = (const float*)d_in[10];
    const float* Winv = (const float*)d_in[11]; const float* binv = (const float*)d_in[12];
    const float* Wdw  = (const float*)d_in[13]; const float* bdw  = (const float*)d_in[14];
    const float* Wpt  = (const float*)d_in[15];
    float* out = (float*)d_out;               // f32 output (the R3-R5 bug)

    const int WSMALL = DIMC * DIMC;
    const int WINVN  = HID2 * DIMC;
    const int WPTN   = DIMC * HIDC;

    char* basep = (char*)d_ws;
    size_t off = 0;
    auto alloc = [&](size_t bytes) -> char* {
        char* p = basep + off;
        off += (bytes + 255) & ~(size_t)255;
        return p;
    };
    float* modsb = (float*)alloc((size_t)2 * 6 * DIMC * 4);
    float* kvb   = (float*)alloc((size_t)KVELEMS * 4);
    bf16* wqb = (bf16*)alloc((size_t)WSMALL * 2);
    bf16* wkb = (bf16*)alloc((size_t)WSMALL * 2);
    bf16* wvb = (bf16*)alloc((size_t)WSMALL * 2);
    bf16* wob = (bf16*)alloc((size_t)WSMALL * 2);
    bf16* wib = (bf16*)alloc((size_t)WINVN * 2);
    bf16* wpb = (bf16*)alloc((size_t)WPTN * 2);
    bf16*  bx  = (bf16*)alloc((size_t)NTOK * DIMC * 2);    // rms-x / attn-out / ffn-y (bf16)
    float* bh2 = (float*)alloc((size_t)NTOK * DIMC * 4);   // residual trunk (f32)
    char* R    = alloc((size_t)33030144);                   // overlay region
    // attention phase overlay (per batch):
    bf16* qb = (bf16*)R;
    bf16* kb = (bf16*)(R + (size_t)NSEQ * DIMC * 2);
    bf16* vb = (bf16*)(R + (size_t)2 * NSEQ * DIMC * 2);
    // FFN phase overlay (per 1024-token chunk):
    bf16* bbig_c = (bf16*)R;                               // 1280 x HID2
    bf16* bglu_c = (bf16*)(R + (size_t)1280 * HID2 * 2);   // 1024 x HIDC

    // weight conversions f32 -> bf16
    cvt_w_kernel<<<(WSMALL / 4 + 255) / 256, 256, 0, stream>>>(Wq, wqb, WSMALL / 4);
    cvt_w_kernel<<<(WSMALL / 4 + 255) / 256, 256, 0, stream>>>(Wk, wkb, WSMALL / 4);
    cvt_w_kernel<<<(WSMALL / 4 + 255) / 256, 256, 0, stream>>>(Wv, wvb, WSMALL / 4);
    cvt_w_kernel<<<(WSMALL / 4 + 255) / 256, 256, 0, stream>>>(Wo, wob, WSMALL / 4);
    cvt_w_kernel<<<(WINVN / 4 + 255) / 256, 256, 0, stream>>>(Winv, wib, WINVN / 4);
    cvt_w_kernel<<<(WPTN / 4 + 255) / 256, 256, 0, stream>>>(Wpt, wpb, WPTN / 4);

    mods_kernel<<<54, 256, 0, stream>>>(sst, temb, modsb);
    rmsmod_kernel<<<NTOK, 256, 0, stream>>>(h_in, modsb, 0, 1, bx);
    zero_kernel<<<(KVELEMS + 255) / 256, 256, 0, stream>>>(kvb, KVELEMS);

    // attention, per batch
    for (int b = 0; b < 2; ++b) {
        bf16* bxb = bx + (size_t)b * NSEQ * DIMC;
        float* kvbb = kvb + (size_t)b * 16 * KVH;
        dim3 gq(NSEQ / 128, DIMC / 128);   // 32 x 9
        gemm_kernel<0, bf16><<<gq, 256, 0, stream>>>(bxb, wqb, bq_, nullptr, 0, 0, nullptr,
                                                     qb, DIMC, DIMC, 0, 1 << 30);
        gemm_kernel<0, bf16><<<gq, 256, 0, stream>>>(bxb, wkb, bk_, nullptr, 0, 0, nullptr,
                                                     kb, DIMC, DIMC, 0, 1 << 30);
        gemm_kernel<1, bf16><<<gq, 256, 0, stream>>>(bxb, wvb, bv_, nullptr, 0, 0, nullptr,
                                                     vb, DIMC, DIMC, 0, 1 << 30);
        attn_kv_kernel<<<dim3(32, 16), 256, 0, stream>>>(kb, vb, kvbb);
        attn_out_kernel<<<dim3(32, 16), 256, 0, stream>>>(qb, kvbb, bxb);  // bxb := attn result
    }
    // Wo proj + gate_msa*attn + residual(h_in f32) -> bh2 (f32 trunk)
    gemm_kernel<2, float><<<dim3(NTOK / 128, DIMC / 128), 256, 0, stream>>>(
        bx, wob, bo_, modsb, 2, 0, h_in, bh2, DIMC, DIMC, 0, 1 << 30);
    // y = rms(bh2)*(1+scale_mlp)+shift_mlp -> bx
    rmsmod_kernel<<<NTOK, 256, 0, stream>>>(bh2, modsb, 3, 4, bx);

    // FFN: per batch, per 1024-token chunk (halo 128 rows each side for dwconv)
    for (int b = 0; b < 2; ++b) {
        const bf16* yb = bx + (size_t)b * NSEQ * DIMC;
        for (int c = 0; c < 4; ++c) {
            int r0 = c * 1024;
            int lo = (c == 0) ? 1 : 0;     // 128-row tile units over 1280-row buffer
            int hi = (c == 3) ? 9 : 10;
            gemm_kernel<3, bf16><<<dim3(10, HID2 / 128), 256, 0, stream>>>(
                yb + (ptrdiff_t)(r0 - 128) * DIMC, wib, binv, nullptr, 0, 0, nullptr,
                bbig_c, HID2, DIMC, lo, hi);
            dwglu_kernel<<<dim3(1024, HIDC / 256), 256, 0, stream>>>(bbig_c, Wdw, bdw, r0, bglu_c);
            gemm_kernel<4, float><<<dim3(8, DIMC / 128), 256, 0, stream>>>(
                bglu_c, wpb, nullptr, modsb, 5, b * NSEQ + r0,
                bh2 + ((size_t)b * NSEQ + r0) * DIMC,
                out + ((size_t)b * NSEQ + r0) * DIMC, DIMC, HIDC, 0, 1 << 30);
        }
    }
}

// Round 8
// 1224.038 us; speedup vs baseline: 1.6036x; 1.6036x over previous
//
#include <hip/hip_runtime.h>
#include <hip/hip_bf16.h>

typedef __hip_bfloat16 bf16;
typedef short short8 __attribute__((ext_vector_type(8)));   // 8 bf16 bit-patterns (4 VGPRs)
typedef float floatx4 __attribute__((ext_vector_type(4)));
typedef int int4v __attribute__((ext_vector_type(4)));

#define DIMC 1152
#define NTOK 8192    // B*N
#define NSEQ 4096
#define HD 72
#define HDP 73       // HD + 1 (padded-ones value column)
#define HIDC 4608
#define HID2 9216
#define QKVN 3456    // 3*DIMC
#define KVH (HD * HDP)            // 5256 per (b,h)
#define KVELEMS (32 * KVH)
#define PZ ((size_t)2048 * DIMC)  // split-K partial plane (per 2048-row chunk)

__device__ __forceinline__ float b2f(bf16 x) { return __bfloat162float(x); }
__device__ __forceinline__ bf16 f2b(float x) { return __float2bfloat16(x); }
__device__ __forceinline__ void st(float* p, float v) { *p = v; }
__device__ __forceinline__ void st(bf16* p, float v)  { *p = f2b(v); }
__device__ __forceinline__ float tf(float x) { return x; }
__device__ __forceinline__ float tf(bf16 x)  { return __bfloat162float(x); }

// ---------------- f32 -> bf16 weight conversion ----------------
__global__ void cvt_w_kernel(const float* __restrict__ src, bf16* __restrict__ dst, int n4) {
    int i = blockIdx.x * 256 + threadIdx.x;
    if (i >= n4) return;
    floatx4 v = ((const floatx4*)src)[i];
    bf16* o = dst + (size_t)i * 4;
    o[0] = f2b(v[0]); o[1] = f2b(v[1]); o[2] = f2b(v[2]); o[3] = f2b(v[3]);
}

__global__ void zero_kernel(float* __restrict__ p, int n) {
    int i = blockIdx.x * 256 + threadIdx.x;
    if (i < n) p[i] = 0.0f;
}

// ---------------- concat 3 bias vectors ----------------
__global__ void bias3_kernel(const float* __restrict__ a, const float* __restrict__ b,
                             const float* __restrict__ c, float* __restrict__ o) {
    int i = blockIdx.x * 256 + threadIdx.x;
    if (i < DIMC) { o[i] = a[i]; o[i + DIMC] = b[i]; o[i + 2 * DIMC] = c[i]; }
}

// ---------------- mods = scale_shift_table + temb.reshape(B,6,D) ----------------
__global__ void mods_kernel(const float* __restrict__ sst, const float* __restrict__ temb,
                            float* __restrict__ mods) {
    int i = blockIdx.x * 256 + threadIdx.x;
    if (i < 2 * 6 * DIMC) {
        int j = i % (6 * DIMC);
        mods[i] = sst[j] + temb[i];
    }
}

// ---------------- x = rms(h)*(1+scale)+shift; out bf16 ----------------
template<typename T>
__global__ void rmsmod_kernel(const T* __restrict__ h, const float* __restrict__ mods,
                              int shift_idx, int scale_idx, bf16* __restrict__ xout) {
    int token = blockIdx.x;            // 0..8191
    int b = token >> 12;
    int tid = threadIdx.x;
    int wave = tid >> 6, lane = tid & 63;
    const T* hp = h + (size_t)token * DIMC;

    float s = 0.f;
    for (int d = tid; d < DIMC; d += 256) { float v = tf(hp[d]); s += v * v; }
    #pragma unroll
    for (int off = 32; off > 0; off >>= 1) s += __shfl_down(s, off);
    __shared__ float wsum[4];
    if (lane == 0) wsum[wave] = s;
    __syncthreads();
    float tot = wsum[0] + wsum[1] + wsum[2] + wsum[3];
    float r = rsqrtf(tot / (float)DIMC + 1e-6f);

    const float* sh = mods + (size_t)(b * 6 + shift_idx) * DIMC;
    const float* sc = mods + (size_t)(b * 6 + scale_idx) * DIMC;
    bf16* xo = xout + (size_t)token * DIMC;
    for (int d = tid; d < DIMC; d += 256) {
        float v = tf(hp[d]);
        xo[d] = f2b(v * r * (1.f + sc[d]) + sh[d]);
    }
}

// ---------------- MFMA GEMM: out = epilogue(A @ W^T); A (M,Kfull) bf16, W (N,Kfull) bf16 ----------------
// MODE 0: QKV fused: acc+bias, relu iff col<2304      -> bf16 (N=3456)
// MODE 2: gate*(acc+bias)+resid(f32)                   -> bf16 trunk
// MODE 3: silu(acc+bias)                               -> bf16
// MODE 5: raw partial acc (split-K via blockIdx.z)     -> f32 at zstride*z
// K loop covers [z*Klen, z*Klen+Klen); bm tiles outside [bm_lo,bm_hi) skipped.
template<int MODE, typename OT>
__global__ __launch_bounds__(256, 2)
void gemm_kernel(const bf16* __restrict__ A, const bf16* __restrict__ W,
                 const float* __restrict__ bias, const float* __restrict__ mods,
                 int gate_idx, int m_off, const float* __restrict__ resid,
                 OT* __restrict__ out, int N, int Kfull, int Klen,
                 size_t zstride, int bm_lo, int bm_hi) {
    const int bm = blockIdx.x;
    if (bm < bm_lo || bm >= bm_hi) return;
    const int koff = blockIdx.z * Klen;
    __shared__ short As[128 * 40];   // 128 rows x 32 k, padded stride 40
    __shared__ short Bs[128 * 40];
    const int tid = threadIdx.x;
    const int wave = tid >> 6;
    const int lane = tid & 63;
    const int quad = lane >> 4;
    const int l16 = lane & 15;
    const int wm = (wave & 1) * 64;
    const int wn = (wave >> 1) * 64;
    const int bn = blockIdx.y;

    floatx4 acc[4][4];
    #pragma unroll
    for (int i = 0; i < 4; i++)
        #pragma unroll
        for (int j = 0; j < 4; j++)
            #pragma unroll
            for (int r = 0; r < 4; r++) acc[i][j][r] = 0.0f;

    const int c0 = tid, c1 = tid + 256;
    const int ar0 = c0 >> 2, ac0 = (c0 & 3) * 8;
    const int ar1 = c1 >> 2, ac1 = (c1 & 3) * 8;
    const bf16* Abase = A + (size_t)(bm * 128) * Kfull + koff;
    const bf16* Wbase = W + (size_t)(bn * 128) * Kfull + koff;

    for (int k0 = 0; k0 < Klen; k0 += 32) {
        __syncthreads();
        *(int4v*)&As[ar0 * 40 + ac0] = *(const int4v*)(Abase + (size_t)ar0 * Kfull + k0 + ac0);
        *(int4v*)&As[ar1 * 40 + ac1] = *(const int4v*)(Abase + (size_t)ar1 * Kfull + k0 + ac1);
        *(int4v*)&Bs[ar0 * 40 + ac0] = *(const int4v*)(Wbase + (size_t)ar0 * Kfull + k0 + ac0);
        *(int4v*)&Bs[ar1 * 40 + ac1] = *(const int4v*)(Wbase + (size_t)ar1 * Kfull + k0 + ac1);
        __syncthreads();
        short8 af[4], bfr[4];
        #pragma unroll
        for (int i = 0; i < 4; i++) {
            af[i]  = *(const short8*)&As[(wm + i * 16 + l16) * 40 + quad * 8];
            bfr[i] = *(const short8*)&Bs[(wn + i * 16 + l16) * 40 + quad * 8];
        }
        #pragma unroll
        for (int i = 0; i < 4; i++)
            #pragma unroll
            for (int j = 0; j < 4; j++)
                acc[i][j] = __builtin_amdgcn_mfma_f32_16x16x32_bf16(af[i], bfr[j], acc[i][j], 0, 0, 0);
    }

    #pragma unroll
    for (int i = 0; i < 4; i++) {
        #pragma unroll
        for (int j = 0; j < 4; j++) {
            const int col = bn * 128 + wn + j * 16 + l16;
            #pragma unroll
            for (int r = 0; r < 4; r++) {
                const int m = bm * 128 + wm + i * 16 + quad * 4 + r;
                float v = acc[i][j][r];
                float o;
                if (MODE == 0) {
                    o = v + bias[col];
                    if (col < 2 * DIMC) o = fmaxf(o, 0.f);
                } else if (MODE == 2) {
                    int b = (m + m_off) >> 12;
                    o = mods[(size_t)(b * 6 + gate_idx) * DIMC + col] * (v + bias[col])
                        + resid[(size_t)m * DIMC + col];
                } else if (MODE == 3) {
                    float sv = v + bias[col];
                    o = sv / (1.f + __expf(-sv));
                } else {  // MODE 5: raw partial
                    o = v;
                }
                st(&out[zstride * blockIdx.z + (size_t)m * N + col], o);
            }
        }
    }
}

// ---------------- split-K reduce: out = trunk + gate_mlp * (p0+p1+p2+p3) ----------------
__global__ void reduce_kernel(const float* __restrict__ part, const bf16* __restrict__ trunk,
                              const float* __restrict__ mods, int b, int r0,
                              float* __restrict__ out) {
    int i = blockIdx.x * 256 + threadIdx.x;          // 0 .. 2048*1152-1
    int col = i % DIMC;
    float s = part[i] + part[i + PZ] + part[i + 2 * PZ] + part[i + 3 * PZ];
    size_t gidx = ((size_t)b * NSEQ + r0) * DIMC + i;
    float gate = mods[(size_t)(b * 6 + 5) * DIMC + col];
    out[gidx] = b2f(trunk[gidx]) + gate * s;
}

// ---------------- attention phase A: kv[h][d][e] += sum_n k[n,d]*vpad[n,e]; qkv stride 3456 ----------------
__global__ __launch_bounds__(256)
void attn_kv_kernel(const bf16* __restrict__ qkv, float* __restrict__ kv, int b) {
    int chunk = blockIdx.x;   // 32 chunks of 128 tokens
    int h = blockIdx.y;       // 16 heads
    __shared__ bf16 kl[128 * HD];
    __shared__ bf16 vl[128 * HDP];
    int tid = threadIdx.x;
    size_t rowbase = ((size_t)(b * NSEQ) + (size_t)chunk * 128) * QKVN + h * HD;
    for (int idx = tid; idx < 128 * HD; idx += 256) {
        int n = idx / HD, d = idx % HD;
        kl[idx] = qkv[rowbase + (size_t)n * QKVN + DIMC + d];
    }
    for (int idx = tid; idx < 128 * HDP; idx += 256) {
        int n = idx / HDP, e = idx % HDP;
        vl[idx] = (e == HD) ? f2b(1.0f) : qkv[rowbase + (size_t)n * QKVN + 2 * DIMC + e];
    }
    __syncthreads();
    for (int cell = tid; cell < KVH; cell += 256) {
        int d = cell / HDP, e = cell % HDP;
        float acc = 0.f;
        #pragma unroll 8
        for (int n = 0; n < 128; ++n)
            acc += b2f(kl[n * HD + d]) * b2f(vl[n * HDP + e]);
        atomicAdd(&kv[(size_t)h * KVH + cell], acc);
    }
}

// ---------------- attention phase B: out[n,e] = (q.kv[:,e]) / (q.kv[:,72]+eps) ----------------
__global__ __launch_bounds__(256, 2)
void attn_out_kernel(const bf16* __restrict__ qkv, const float* __restrict__ kv,
                     bf16* __restrict__ outa, int b) {
    int chunk = blockIdx.x;
    int h = blockIdx.y;
    __shared__ float kvt[HDP * HD];   // kvt[e*72+d]
    __shared__ bf16 ql[128 * HD];
    int tid = threadIdx.x;
    for (int i = tid; i < KVH; i += 256) {
        int d = i / HDP, e = i % HDP;
        kvt[e * HD + d] = kv[(size_t)h * KVH + i];
    }
    size_t rowbase = ((size_t)(b * NSEQ) + (size_t)chunk * 128) * QKVN + h * HD;
    for (int idx = tid; idx < 128 * HD; idx += 256) {
        int n = idx / HD, d = idx % HD;
        ql[idx] = qkv[rowbase + (size_t)n * QKVN + d];
    }
    __syncthreads();
    int n = tid >> 1;
    int hf = tid & 1;
    float qr[HD];
    #pragma unroll
    for (int d = 0; d < HD; ++d) qr[d] = b2f(ql[n * HD + d]);
    float den = 0.f;
    #pragma unroll
    for (int d = 0; d < HD; ++d) den += qr[d] * kvt[HD * HD + d];
    den += 1e-15f;
    float inv = 1.0f / den;
    size_t obase = ((size_t)chunk * 128 + n) * DIMC + h * HD;   // outa pre-offset by batch
    for (int ei = 0; ei < 36; ++ei) {
        int e = hf * 36 + ei;
        const float* kr = &kvt[e * HD];
        float s = 0.f;
        #pragma unroll
        for (int d = 0; d < HD; ++d) s += qr[d] * kr[d];
        outa[obase + e] = f2b(s * inv);
    }
}

// ---------------- depthwise conv k=3 + bias + GLU(silu); 2048-row chunk w/ 128-row halo ----------------
// ybuf rows 0..2303 = batch rows [r0-128, r0+2176); local out row nl -> buf row nl+128.
__global__ void dwglu_kernel(const bf16* __restrict__ ybuf, const float* __restrict__ wdw,
                             const float* __restrict__ bdw, int r0, bf16* __restrict__ outg) {
    int nl = blockIdx.x;                        // 0..2047 local
    int g = r0 + nl;                            // global row within batch
    int c = blockIdx.y * 256 + threadIdx.x;     // 0..4607
    int row = nl + 128;
    size_t base = (size_t)row * HID2;
    int cg = c + HIDC;
    float xm1 = (g > 0)        ? b2f(ybuf[base - HID2 + c])  : 0.f;
    float x0  =                  b2f(ybuf[base + c]);
    float xp1 = (g < NSEQ - 1) ? b2f(ybuf[base + HID2 + c])  : 0.f;
    float gm1 = (g > 0)        ? b2f(ybuf[base - HID2 + cg]) : 0.f;
    float g0  =                  b2f(ybuf[base + cg]);
    float gp1 = (g < NSEQ - 1) ? b2f(ybuf[base + HID2 + cg]) : 0.f;
    float a = xm1 * wdw[c * 3 + 0] + x0 * wdw[c * 3 + 1] + xp1 * wdw[c * 3 + 2] + bdw[c];
    float gg = gm1 * wdw[cg * 3 + 0] + g0 * wdw[cg * 3 + 1] + gp1 * wdw[cg * 3 + 2] + bdw[cg];
    float sg = gg / (1.f + __expf(-gg));
    outg[(size_t)nl * HIDC + c] = f2b(a * sg);
}

extern "C" void kernel_launch(void* const* d_in, const int* in_sizes, int n_in,
                              void* d_out, int out_size, void* d_ws, size_t ws_size,
                              hipStream_t stream) {
    const float* h_in = (const float*)d_in[0];
    const float* temb = (const float*)d_in[1];
    const float* sst  = (const float*)d_in[2];
    const float* Wq = (const float*)d_in[3];   const float* bq_ = (const float*)d_in[4];
    const float* Wk = (const float*)d_in[5];   const float* bk_ = (const float*)d_in[6];
    const float* Wv = (const float*)d_in[7];   const float* bv_ = (const float*)d_in[8];
    const float* Wo = (const float*)d_in[9];   const float* bo_ = (const float*)d_in[10];
    const float* Winv = (const float*)d_in[11]; const float* binv = (const float*)d_in[12];
    const float* Wdw  = (const float*)d_in[13]; const float* bdw  = (const float*)d_in[14];
    const float* Wpt  = (const float*)d_in[15];
    float* out = (float*)d_out;

    const int WSMALL = DIMC * DIMC;       // 1,327,104
    const int WINVN  = HID2 * DIMC;
    const int WPTN   = DIMC * HIDC;

    char* basep = (char*)d_ws;
    size_t off = 0;
    auto alloc = [&](size_t bytes) -> char* {
        char* p = basep + off;
        off += (bytes + 255) & ~(size_t)255;
        return p;
    };
    float* modsb = (float*)alloc((size_t)2 * 6 * DIMC * 4);
    float* kvb   = (float*)alloc((size_t)KVELEMS * 4);
    float* bqkv  = (float*)alloc((size_t)QKVN * 4);
    bf16* wqkv = (bf16*)alloc((size_t)3 * WSMALL * 2);      // [Wq;Wk;Wv] rows
    bf16* wob  = (bf16*)alloc((size_t)WSMALL * 2);
    bf16* wib  = (bf16*)alloc((size_t)WINVN * 2);
    bf16* wpb  = (bf16*)alloc((size_t)WPTN * 2);
    bf16* bx    = (bf16*)alloc((size_t)NTOK * DIMC * 2);    // rms-x / attn-out / ffn-y
    bf16* trunk = (bf16*)alloc((size_t)NTOK * DIMC * 2);    // residual trunk (bf16)
    char* R     = alloc((size_t)61341696);                  // overlay region (61.4 MB)
    // attention phase: qkv (8192 x 3456 bf16 = 56.6 MB)
    bf16* qkvb = (bf16*)R;
    // FFN phase overlay (per 2048-row chunk):
    bf16*  bglu_c   = (bf16*)R;                             // 2048 x 4608 bf16 (18.9 MB)
    bf16*  bbig_c   = (bf16*)(R + (size_t)18874368);        // 2304 x 9216 bf16 (42.5 MB)
    float* partials = (float*)(R + (size_t)18874368);       // 4 x 2048 x 1152 f32 (aliases bbig)

    // weight conversions f32 -> bf16
    cvt_w_kernel<<<(WSMALL / 4 + 255) / 256, 256, 0, stream>>>(Wq, wqkv, WSMALL / 4);
    cvt_w_kernel<<<(WSMALL / 4 + 255) / 256, 256, 0, stream>>>(Wk, wqkv + WSMALL, WSMALL / 4);
    cvt_w_kernel<<<(WSMALL / 4 + 255) / 256, 256, 0, stream>>>(Wv, wqkv + 2 * WSMALL, WSMALL / 4);
    cvt_w_kernel<<<(WSMALL / 4 + 255) / 256, 256, 0, stream>>>(Wo, wob, WSMALL / 4);
    cvt_w_kernel<<<(WINVN / 4 + 255) / 256, 256, 0, stream>>>(Winv, wib, WINVN / 4);
    cvt_w_kernel<<<(WPTN / 4 + 255) / 256, 256, 0, stream>>>(Wpt, wpb, WPTN / 4);
    bias3_kernel<<<5, 256, 0, stream>>>(bq_, bk_, bv_, bqkv);

    mods_kernel<<<54, 256, 0, stream>>>(sst, temb, modsb);
    rmsmod_kernel<float><<<NTOK, 256, 0, stream>>>(h_in, modsb, 0, 1, bx);
    zero_kernel<<<(KVELEMS + 255) / 256, 256, 0, stream>>>(kvb, KVELEMS);

    // fused QKV: (8192 x 1152) @ (3456 x 1152)^T -> qkvb, grid 64x27 = 1728 blocks
    gemm_kernel<0, bf16><<<dim3(NTOK / 128, QKVN / 128), 256, 0, stream>>>(
        bx, wqkv, bqkv, nullptr, 0, 0, nullptr, qkvb, QKVN, DIMC, DIMC, 0, 0, 1 << 30);

    // linear attention per batch
    for (int b = 0; b < 2; ++b) {
        float* kvbb = kvb + (size_t)b * 16 * KVH;
        attn_kv_kernel<<<dim3(32, 16), 256, 0, stream>>>(qkvb, kvbb, b);
        attn_out_kernel<<<dim3(32, 16), 256, 0, stream>>>(qkvb, kvbb,
                                                          bx + (size_t)b * NSEQ * DIMC, b);
    }
    // Wo + gate_msa*attn + resid(h_in) -> trunk (bf16), grid 64x9 = 576 blocks
    gemm_kernel<2, bf16><<<dim3(NTOK / 128, DIMC / 128), 256, 0, stream>>>(
        bx, wob, bo_, modsb, 2, 0, h_in, trunk, DIMC, DIMC, DIMC, 0, 0, 1 << 30);
    // y = rms(trunk)*(1+scale_mlp)+shift_mlp -> bx
    rmsmod_kernel<bf16><<<NTOK, 256, 0, stream>>>(trunk, modsb, 3, 4, bx);

    // FFN: per batch, per 2048-row chunk
    for (int b = 0; b < 2; ++b) {
        for (int c = 0; c < 2; ++c) {
            int r0 = c * 2048;
            int lo = (c == 0) ? 1 : 0;     // trim halo tiles (18 x 128 rows over 2304-row buf)
            int hi = (c == 0) ? 18 : 17;
            const bf16* Ainv = bx + ((size_t)(b * NSEQ + r0)) * DIMC - (size_t)128 * DIMC;
            // W_inv + SiLU: grid 18x72 = 1296 blocks
            gemm_kernel<3, bf16><<<dim3(18, HID2 / 128), 256, 0, stream>>>(
                Ainv, wib, binv, nullptr, 0, 0, nullptr, bbig_c, HID2, DIMC, DIMC, 0, lo, hi);
            // depthwise conv + GLU: 2048 x 18 blocks
            dwglu_kernel<<<dim3(2048, HIDC / 256), 256, 0, stream>>>(bbig_c, Wdw, bdw, r0, bglu_c);
            // W_pt split-K x4: grid 16x9x4 = 576 blocks -> f32 partials
            gemm_kernel<5, float><<<dim3(16, DIMC / 128, 4), 256, 0, stream>>>(
                bglu_c, wpb, nullptr, nullptr, 0, 0, nullptr, partials, DIMC, HIDC, HIDC / 4,
                PZ, 0, 1 << 30);
            // reduce + gate_mlp + trunk -> out
            reduce_kernel<<<(int)(PZ / 256), 256, 0, stream>>>(partials, trunk, modsb, b, r0, out);
        }
    }
}